// Round 4
// baseline (257.250 us; speedup 1.0000x reference)
//
#include <hip/hip_runtime.h>
#include <math.h>

#define NN   1200
#define EPSF 1e-8f

typedef _Float16 h8 __attribute__((ext_vector_type(8)));
typedef __attribute__((ext_vector_type(16))) float f16v;

#define AHI 0
#define ALO 16384
#define BHI 32768
#define BLO 49152

// ---- kA1: mean over k_shot + transpose -> supmean[b*125+s][c] fp32 ---------
__global__ __launch_bounds__(256) void kA1(const float* __restrict__ sxf,
                                           float* __restrict__ supmean) {
  const int blk = blockIdx.x;                    // b*25 + w*5 + ck
  const int b = blk / 25, rem = blk % 25, w = rem / 5, ck = rem % 5;
  const int c0 = ck * 128;
  const int tid = threadIdx.x;
  __shared__ float lds[3200];                    // [c_local(128)][j(25)]
  const float* base = sxf + (size_t)(b * 25 + w * 5) * 16000 + (size_t)c0 * 25;

  for (int f0 = tid * 4; f0 < 3200; f0 += 1024) {
    float4 a  = *(const float4*)(base + f0);
    float4 b1 = *(const float4*)(base + 16000 + f0);
    float4 c1 = *(const float4*)(base + 32000 + f0);
    float4 d1 = *(const float4*)(base + 48000 + f0);
    float4 e1 = *(const float4*)(base + 64000 + f0);
    lds[f0 + 0] = (a.x + b1.x + c1.x + d1.x + e1.x) * 0.2f;
    lds[f0 + 1] = (a.y + b1.y + c1.y + d1.y + e1.y) * 0.2f;
    lds[f0 + 2] = (a.z + b1.z + c1.z + d1.z + e1.z) * 0.2f;
    lds[f0 + 3] = (a.w + b1.w + c1.w + d1.w + e1.w) * 0.2f;
  }
  __syncthreads();
  for (int g = tid; g < 3200; g += 256) {
    int j = g >> 7, cc = g & 127;
    supmean[(size_t)(b * 125 + w * 25 + j) * 640 + c0 + cc] = lds[cc * 25 + j];
  }
}

// ---- kA2: L2-normalize rows + split to f16 hi/lo ---------------------------
// sup layout: [b][hl][s][c] ushort(f16 bits); b stride 160000, hl stride 80000
__global__ __launch_bounds__(256) void kA2(const float* __restrict__ supmean,
                                           ushort* __restrict__ sup) {
  const int r = blockIdx.x * 4 + (threadIdx.x >> 6);    // 0..1999
  const int lane = threadIdx.x & 63;
  const int b = r / 125, s = r % 125;
  const float* row = supmean + (size_t)r * 640;
  float4 v0 = *(const float4*)(row + lane * 4);
  float4 v1 = *(const float4*)(row + 256 + lane * 4);
  float4 v2 = {0.f, 0.f, 0.f, 0.f};
  if (lane < 32) v2 = *(const float4*)(row + 512 + lane * 4);
  float ssq = v0.x*v0.x + v0.y*v0.y + v0.z*v0.z + v0.w*v0.w
            + v1.x*v1.x + v1.y*v1.y + v1.z*v1.z + v1.w*v1.w
            + v2.x*v2.x + v2.y*v2.y + v2.z*v2.z + v2.w*v2.w;
#pragma unroll
  for (int d = 32; d; d >>= 1) ssq += __shfl_xor(ssq, d);
  const float rinv = 1.f / (sqrtf(ssq) + EPSF);
  ushort* dst = sup + (size_t)b * 160000 + (size_t)s * 640;
#pragma unroll
  for (int seg = 0; seg < 3; ++seg) {
    if (seg == 2 && lane >= 32) break;
    float4 v = (seg == 0) ? v0 : ((seg == 1) ? v1 : v2);
    int c = seg * 256 + lane * 4;
    float vv[4] = { v.x * rinv, v.y * rinv, v.z * rinv, v.w * rinv };
    ushort hh[4], ll[4];
#pragma unroll
    for (int u = 0; u < 4; ++u) {
      _Float16 h = (_Float16)vv[u];
      float rr = vv[u] - (float)h;
      _Float16 l = (_Float16)rr;
      hh[u] = __builtin_bit_cast(ushort, h);
      ll[u] = __builtin_bit_cast(ushort, l);
    }
    uint2 ph = { (uint)hh[0] | ((uint)hh[1] << 16), (uint)hh[2] | ((uint)hh[3] << 16) };
    uint2 pl = { (uint)ll[0] | ((uint)ll[1] << 16), (uint)ll[2] | ((uint)ll[3] << 16) };
    *(uint2*)(dst + c) = ph;
    *(uint2*)(dst + 80000 + c) = pl;
  }
}

// ---- kG: batched tile GEMM, 125 query-rows x 128 support-cols per block ----
__device__ __forceinline__ void load_chunk(const float* __restrict__ qbase5,
                                           const ushort* __restrict__ supb,
                                           int k0, int tid,
                                           float (&aq)[8][4], uint4 (&bq)[8]) {
#pragma unroll
  for (int j = 0; j < 8; ++j) {
    int t = tid + j * 256;
    if (t < 2000) {
      int q = t / 400, rem = t % 400, c4 = rem / 25, i = rem % 25;
      const float* qp = qbase5 + (size_t)q * 16000 + (size_t)(k0 + c4 * 4) * 25 + i;
      aq[j][0] = qp[0]; aq[j][1] = qp[25]; aq[j][2] = qp[50]; aq[j][3] = qp[75];
    }
  }
#pragma unroll
  for (int j = 0; j < 8; ++j) {
    int t = tid + j * 256;
    if (t < 2000) {
      int hl = (t >= 1000) ? 1 : 0;
      int r2 = t - hl * 1000;
      int row = r2 >> 3, seg = r2 & 7;
      bq[j] = *(const uint4*)(supb + (size_t)hl * 80000 + (size_t)row * 640 + k0 + seg * 8);
    }
  }
}

__device__ __forceinline__ void store_chunk(char* st, int tid,
                                            float (&aq)[8][4], uint4 (&bq)[8],
                                            float (&pn)[8]) {
#pragma unroll
  for (int j = 0; j < 8; ++j) {
    int t = tid + j * 256;
    if (t < 2000) {
      int q = t / 400, rem = t % 400, c4 = rem / 25, i = rem % 25;
      int row = q * 25 + i;
      ushort hh[4], ll[4];
      float ss = 0.f;
#pragma unroll
      for (int u = 0; u < 4; ++u) {
        float v = aq[j][u];
        ss = fmaf(v, v, ss);
        _Float16 h = (_Float16)v;
        float rr = v - (float)h;
        _Float16 l = (_Float16)rr;
        hh[u] = __builtin_bit_cast(ushort, h);
        ll[u] = __builtin_bit_cast(ushort, l);
      }
      pn[j] += ss;
      uint2 ph = { (uint)hh[0] | ((uint)hh[1] << 16), (uint)hh[2] | ((uint)hh[3] << 16) };
      uint2 pl = { (uint)ll[0] | ((uint)ll[1] << 16), (uint)ll[2] | ((uint)ll[3] << 16) };
      int off = (row * 128 + c4 * 8) ^ ((row & 7) << 4);
      *(uint2*)(st + AHI + off) = ph;
      *(uint2*)(st + ALO + off) = pl;
    }
  }
#pragma unroll
  for (int j = 0; j < 8; ++j) {
    int t = tid + j * 256;
    if (t < 2000) {
      int hl = (t >= 1000) ? 1 : 0;
      int r2 = t - hl * 1000;
      int row = r2 >> 3, seg = r2 & 7;
      int off = (row * 128 + seg * 16) ^ ((row & 7) << 4);
      *(uint4*)(st + BHI + hl * 16384 + off) = bq[j];
    }
  }
}

__global__ __launch_bounds__(256, 1) void kG(const float* __restrict__ qxf,
                                             const ushort* __restrict__ sup,
                                             float* __restrict__ Sg) {
  const int blk = blockIdx.x;                 // b*15 + qg
  const int b = blk / 15, qg = blk % 15;
  const int tid = threadIdx.x;
  const int lane = tid & 63, l31 = lane & 31, hi32 = lane >> 5;
  const int wv = tid >> 6, wr = wv >> 1, wc = wv & 1;
  __shared__ __align__(16) char st[65536];
  __shared__ float nsq[128], rinv_s[128];

  const float* qbase5 = qxf + (size_t)(b * 75 + qg * 5) * 16000;
  const ushort* supb = sup + (size_t)b * 160000;

  // init: pad rows 125..127 of all planes = 0; nsq = 0
  if (tid < 96) {
    int r = 125 + tid / 32, cb = (tid % 32) * 4;
    int off = (r * 128 + cb) ^ ((r & 7) << 4);
    *(uint*)(st + AHI + off) = 0u; *(uint*)(st + ALO + off) = 0u;
    *(uint*)(st + BHI + off) = 0u; *(uint*)(st + BLO + off) = 0u;
  }
  if (tid < 128) nsq[tid] = 0.f;

  f16v acc[2][2];
#pragma unroll
  for (int rt = 0; rt < 2; ++rt)
#pragma unroll
    for (int ct = 0; ct < 2; ++ct)
#pragma unroll
      for (int r = 0; r < 16; ++r) acc[rt][ct][r] = 0.f;

  float aA[8][4], aB[8][4];
  uint4 bA[8], bB[8];
  float pn[8];
#pragma unroll
  for (int j = 0; j < 8; ++j) pn[j] = 0.f;

  load_chunk(qbase5, supb, 0, tid, aA, bA);

#define MFMA_PHASE()                                                          \
  {                                                                           \
    _Pragma("unroll")                                                         \
    for (int ks = 0; ks < 4; ++ks) {                                          \
      const int kb = ks * 32 + hi32 * 16;                                     \
      h8 ahf[2], alf[2], bhf[2], blf[2];                                      \
      _Pragma("unroll")                                                       \
      for (int rt = 0; rt < 2; ++rt) {                                        \
        int ar = wr * 64 + rt * 32 + l31;                                     \
        int off = (ar * 128 + kb) ^ ((ar & 7) << 4);                          \
        ahf[rt] = *(const h8*)(st + AHI + off);                               \
        alf[rt] = *(const h8*)(st + ALO + off);                               \
      }                                                                       \
      _Pragma("unroll")                                                       \
      for (int ct = 0; ct < 2; ++ct) {                                        \
        int br = wc * 64 + ct * 32 + l31;                                     \
        int off = (br * 128 + kb) ^ ((br & 7) << 4);                          \
        bhf[ct] = *(const h8*)(st + BHI + off);                               \
        blf[ct] = *(const h8*)(st + BLO + off);                               \
      }                                                                       \
      _Pragma("unroll")                                                       \
      for (int rt = 0; rt < 2; ++rt)                                          \
        _Pragma("unroll")                                                     \
        for (int ct = 0; ct < 2; ++ct) {                                      \
          acc[rt][ct] = __builtin_amdgcn_mfma_f32_32x32x16_f16(ahf[rt], bhf[ct], acc[rt][ct], 0, 0, 0); \
          acc[rt][ct] = __builtin_amdgcn_mfma_f32_32x32x16_f16(alf[rt], bhf[ct], acc[rt][ct], 0, 0, 0); \
          acc[rt][ct] = __builtin_amdgcn_mfma_f32_32x32x16_f16(ahf[rt], blf[ct], acc[rt][ct], 0, 0, 0); \
        }                                                                     \
    }                                                                         \
  }

  for (int ch = 0; ch < 10; ch += 2) {
    __syncthreads();
    store_chunk(st, tid, aA, bA, pn);
    if (ch + 1 < 10) load_chunk(qbase5, supb, (ch + 1) * 64, tid, aB, bB);
    __syncthreads();
    MFMA_PHASE();
    __syncthreads();
    store_chunk(st, tid, aB, bB, pn);
    if (ch + 2 < 10) load_chunk(qbase5, supb, (ch + 2) * 64, tid, aA, bA);
    __syncthreads();
    MFMA_PHASE();
  }

  // query norms
#pragma unroll
  for (int j = 0; j < 8; ++j) {
    int t = tid + j * 256;
    if (t < 2000) {
      int q = t / 400, rem = t % 400, i = rem % 25;
      atomicAdd(&nsq[q * 25 + i], pn[j]);
    }
  }
  __syncthreads();
  if (tid < 125) rinv_s[tid] = 1.f / (sqrtf(nsq[tid]) + EPSF);
  __syncthreads();

  // epilogue: Sg[n][i][col]
#pragma unroll
  for (int rt = 0; rt < 2; ++rt) {
#pragma unroll
    for (int r = 0; r < 16; ++r) {
      int rowg = wr * 64 + rt * 32 + (r & 3) + 8 * (r >> 2) + 4 * hi32;
      if (rowg < 125) {
        float rv = rinv_s[rowg];
        int n = b * 75 + qg * 5 + rowg / 25;
        int i = rowg % 25;
#pragma unroll
        for (int ct = 0; ct < 2; ++ct) {
          int col = wc * 64 + ct * 32 + l31;
          Sg[(size_t)n * 3200 + i * 128 + col] = acc[rt][ct][r] * rv;
        }
      }
    }
  }
}

// ---- kT: softmaxes + B + Jacobi + katz + loss; LDS row stride 132 ----------
#define LD 132
__global__ __launch_bounds__(256) void kT(const float* __restrict__ Sg,
                                          const int* __restrict__ qy,
                                          float* __restrict__ out) {
  const int n = blockIdx.x;
  const int tid = threadIdx.x;
  __shared__ __align__(16) float S[25 * LD];     // becomes Tsq in place
  __shared__ __align__(16) float TqsT[25 * LD];
  __shared__ float Bm[625], rhs[25], xv[25], Pk[5];

  const float* sgn = Sg + (size_t)n * 3200;
  for (int idx = tid; idx < 800; idx += 256) {
    int row = idx >> 5, q4 = idx & 31;
    *(float4*)(S + row * LD + q4 * 4) = *(const float4*)(sgn + row * 128 + q4 * 4);
  }
  if (tid < 5) Pk[tid] = 0.f;
  if (tid >= 32 && tid < 57) {                   // zero TqsT pad cols 125..127
    int i = tid - 32;
    TqsT[i * LD + 125] = 0.f; TqsT[i * LD + 126] = 0.f; TqsT[i * LD + 127] = 0.f;
  }
  __syncthreads();

  if (tid < 125) {                               // col softmax (gamma=10) -> TqsT
    float mx = -1e30f;
#pragma unroll
    for (int i = 0; i < 25; ++i) mx = fmaxf(mx, S[i * LD + tid]);
    float sm = 0.f;
#pragma unroll
    for (int i = 0; i < 25; ++i) {
      float e = __expf(10.f * (S[i * LD + tid] - mx));
      TqsT[i * LD + tid] = e; sm += e;
    }
    float rs = 1.f / sm;
#pragma unroll
    for (int i = 0; i < 25; ++i) TqsT[i * LD + tid] *= rs;
  }
  __syncthreads();
  if (tid < 200) {                               // row softmax (gamma=20) in place
    int i = tid >> 3, l = tid & 7;
    float* Srow = S + i * LD;
    float mx = -1e30f;
    for (int ss = l; ss < 125; ss += 8) mx = fmaxf(mx, Srow[ss]);
    mx = fmaxf(mx, __shfl_xor(mx, 1, 8));
    mx = fmaxf(mx, __shfl_xor(mx, 2, 8));
    mx = fmaxf(mx, __shfl_xor(mx, 4, 8));
    float sm = 0.f;
    for (int ss = l; ss < 128; ss += 8) {
      float e = 0.f;
      if (ss < 125) { e = __expf(20.f * (Srow[ss] - mx)); sm += e; }
      Srow[ss] = e;
    }
    sm += __shfl_xor(sm, 1, 8);
    sm += __shfl_xor(sm, 2, 8);
    sm += __shfl_xor(sm, 4, 8);
    float rs = 1.f / sm;
    for (int ss = l; ss < 125; ss += 8) Srow[ss] *= rs;
  }
  __syncthreads();

  for (int ii = tid; ii < 625; ii += 256) {      // B = TqsT . Tsq^T (K=125)
    int i = ii / 25, ip = ii % 25;
    const float* ta = TqsT + i * LD;
    const float* tb = S + ip * LD;
    float4 s4 = { 0.f, 0.f, 0.f, 0.f };
#pragma unroll
    for (int q4 = 0; q4 < 32; ++q4) {
      float4 a4 = *(const float4*)(ta + q4 * 4);
      float4 b4 = *(const float4*)(tb + q4 * 4);
      s4.x = fmaf(a4.x, b4.x, s4.x); s4.y = fmaf(a4.y, b4.y, s4.y);
      s4.z = fmaf(a4.z, b4.z, s4.z); s4.w = fmaf(a4.w, b4.w, s4.w);
    }
    Bm[ii] = (s4.x + s4.y) + (s4.z + s4.w);
  }
  if (tid < 25) {                                // rhs = 1 + 0.5*colsum(Tqs)
    const float* ta = TqsT + tid * LD;
    float4 s4 = { 0.f, 0.f, 0.f, 0.f };
#pragma unroll
    for (int q4 = 0; q4 < 32; ++q4) {
      float4 a4 = *(const float4*)(ta + q4 * 4);
      s4.x += a4.x; s4.y += a4.y; s4.z += a4.z; s4.w += a4.w;
    }
    rhs[tid] = 1.f + 0.5f * ((s4.x + s4.y) + (s4.z + s4.w));
  }
  __syncthreads();

  if (tid < 64) {                                // Jacobi, wave 0, 16 iters
    float Brow[25], x, rh;
    if (tid < 25) {
      rh = rhs[tid]; x = rh;
#pragma unroll
      for (int ip = 0; ip < 25; ++ip) Brow[ip] = Bm[tid * 25 + ip];
    } else {
      rh = 0.f; x = 0.f;
#pragma unroll
      for (int ip = 0; ip < 25; ++ip) Brow[ip] = 0.f;
    }
#pragma unroll
    for (int it = 0; it < 16; ++it) {
      float sum = 0.f;
#pragma unroll
      for (int ip = 0; ip < 25; ++ip) sum = fmaf(Brow[ip], __shfl(x, ip), sum);
      x = rh + 0.25f * sum;
    }
    if (tid < 25) xv[tid] = x;
  }
  __syncthreads();

  if (tid < 125) {                               // katz -> class sums
    float kz = 0.f;
#pragma unroll
    for (int i = 0; i < 25; ++i) kz = fmaf(S[i * LD + tid], xv[i], kz);
    atomicAdd(&Pk[tid / 25], kz);
  }
  __syncthreads();
  if (tid == 0) {
    float den = Pk[0] + Pk[1] + Pk[2] + Pk[3] + Pk[4];
    int y = qy[n];
    float v = -(logf(Pk[y]) - logf(den)) * (1.0f / (float)NN);
    atomicAdd(out, v);
  }
}

extern "C" void kernel_launch(void* const* d_in, const int* in_sizes, int n_in,
                              void* d_out, int out_size, void* d_ws, size_t ws_size,
                              hipStream_t stream) {
  const float* sxf = (const float*)d_in[0];
  const float* qxf = (const float*)d_in[2];
  const int*   qy  = (const int*)d_in[3];
  float* out = (float*)d_out;
  float*  supmean = (float*)d_ws;                        // 5.12 MB
  ushort* sup     = (ushort*)((char*)d_ws + 5120000);    // 5.12 MB
  float*  Sgw     = (float*)((char*)d_ws + 10240000);    // 15.36 MB

  hipMemsetAsync(out, 0, sizeof(float), stream);
  kA1<<<400, 256, 0, stream>>>(sxf, supmean);
  kA2<<<500, 256, 0, stream>>>(supmean, sup);
  kG<<<240, 256, 0, stream>>>(qxf, sup, Sgw);
  kT<<<NN, 256, 0, stream>>>(Sgw, qy, out);
}